// Round 8
// baseline (1076.038 us; speedup 1.0000x reference)
//
#include <hip/hip_runtime.h>
#include <math.h>

#define N_NODES 50000
#define N_EDGES 800000
#define IN_DIMC 128
#define D1 256      // heads*hid (layer-1 output width, also skip width)
#define D3 768      // q|k|v concat width
#define D2ALL 40    // layer-2 q|k|v|skip concat width
#define LCAP 128    // per-node logit slots in LDS (max degree ~60 for Poisson(16))

// ---------------- diagnostic fallback ----------------
__global__ void k_zero(float* __restrict__ out, int n){
  int i = blockIdx.x*blockDim.x + threadIdx.x;
  if (i < n) out[i] = 0.f;
}

// ---------------- edge decode: robust to int32 / int64 edge_index ----------------
__global__ void k_edges(const int* __restrict__ w, int* __restrict__ s0, int* __restrict__ d0){
  __shared__ int is64_s;
  if (threadIdx.x == 0){
    int acc = 0;
    #pragma unroll
    for (int j = 0; j < 17; j++) acc |= w[2*j+1];   // int64 hi-words are 0 (ids<50000)
    is64_s = (acc == 0);
  }
  __syncthreads();
  bool is64 = is64_s;
  int e = blockIdx.x*blockDim.x + threadIdx.x;
  if (e < N_EDGES){
    if (is64){ s0[e] = w[2*e];  d0[e] = w[2*(N_EDGES + e)]; }
    else     { s0[e] = w[e];    d0[e] = w[N_EDGES + e];     }
  }
}

// ---------------- CSR build ----------------
__global__ void k_count(const int* __restrict__ d0, int* __restrict__ deg){
  int e = blockIdx.x*blockDim.x + threadIdx.x;
  if (e < N_EDGES) atomicAdd(&deg[d0[e]], 1);
}

__global__ __launch_bounds__(1024) void k_scan(const int* __restrict__ deg,
                                               int* __restrict__ rowptr,
                                               int* __restrict__ cursor){
  __shared__ int wsum[16];
  __shared__ int carry_s;
  int t = threadIdx.x;
  int w = t >> 6, lane = t & 63;
  if (t == 0){ carry_s = 0; rowptr[0] = 0; }
  __syncthreads();
  for (int base = 0; base < N_NODES; base += 1024){
    int i = base + t;
    int v = (i < N_NODES) ? deg[i] : 0;
    int s = v;
    #pragma unroll
    for (int off = 1; off < 64; off <<= 1){
      int u = __shfl_up(s, off);
      if (lane >= off) s += u;
    }
    if (lane == 63) wsum[w] = s;
    __syncthreads();
    if (w == 0 && lane < 16){
      int ws = wsum[lane];
      #pragma unroll
      for (int off = 1; off < 16; off <<= 1){
        int u = __shfl_up(ws, off);
        if (lane >= off) ws += u;
      }
      wsum[lane] = ws;
    }
    __syncthreads();
    int waveoff = (w == 0) ? 0 : wsum[w-1];
    int incl = carry_s + waveoff + s;
    if (i < N_NODES){
      rowptr[i+1] = incl;
      cursor[i]   = incl - v;
    }
    __syncthreads();
    if (t == 1023) carry_s = incl;
    __syncthreads();
  }
}

__global__ void k_scatter(const int* __restrict__ s0, const int* __restrict__ d0,
                          int* __restrict__ cursor, int* __restrict__ esrc){
  int e = blockIdx.x*blockDim.x + threadIdx.x;
  if (e < N_EDGES){
    int slot = atomicAdd(&cursor[d0[e]], 1);
    esrc[slot] = s0[e];
  }
}

// ---------------- linear: x[N,128] @ (w_sel)[128,256] tiles, 64x128 per block ----
// qkv call: gridDim.x=6 (sel 0..2 -> w0,w1,w2), ostride=768
// skip call: gridDim.x=2 (sel==0 -> w0), ostride=256
__global__ __launch_bounds__(256) void k_lin(const float* __restrict__ x,
        const float* __restrict__ w0, const float* __restrict__ w1,
        const float* __restrict__ w2,
        const float* __restrict__ b0, const float* __restrict__ b1,
        const float* __restrict__ b2,
        float* __restrict__ out, int ostride){
  __shared__ float xs[64][68];
  __shared__ float wls[64][128];
  int t  = threadIdx.x;
  int ty = t >> 4, tx = t & 15;
  int n0   = blockIdx.y * 64;
  int col0 = blockIdx.x * 128;
  int sel  = col0 >> 8;
  int wcol = col0 & 255;
  const float* wptr = sel==0 ? w0 : sel==1 ? w1 : w2;
  const float* bptr = sel==0 ? b0 : sel==1 ? b1 : b2;

  float acc[4][8];
  #pragma unroll
  for (int i=0;i<4;i++)
    #pragma unroll
    for (int j=0;j<8;j++) acc[i][j] = 0.f;

  for (int k0 = 0; k0 < IN_DIMC; k0 += 64){
    #pragma unroll
    for (int q = 0; q < 4; q++){
      int L = (q*256 + t)*4;
      int row = L >> 6, col = L & 63;
      int gr = n0 + row;
      float4 vv = make_float4(0.f,0.f,0.f,0.f);
      if (gr < N_NODES) vv = *(const float4*)(x + (size_t)gr*IN_DIMC + k0 + col);
      *(float4*)&xs[row][col] = vv;
    }
    #pragma unroll
    for (int q = 0; q < 8; q++){
      int L = (q*256 + t)*4;
      int row = L >> 7, col = L & 127;
      float4 vv = *(const float4*)(wptr + (size_t)(k0+row)*256 + wcol + col);
      *(float4*)&wls[row][col] = vv;
    }
    __syncthreads();
    for (int kk = 0; kk < 64; kk += 4){
      float4 aq[4];
      #pragma unroll
      for (int i=0;i<4;i++) aq[i] = *(const float4*)&xs[ty*4+i][kk];
      #pragma unroll
      for (int u=0;u<4;u++){
        float4 b0v = *(const float4*)&wls[kk+u][tx*4];
        float4 b1v = *(const float4*)&wls[kk+u][64 + tx*4];
        #pragma unroll
        for (int i=0;i<4;i++){
          float a = ((const float*)&aq[i])[u];
          acc[i][0] = fmaf(a,b0v.x,acc[i][0]);
          acc[i][1] = fmaf(a,b0v.y,acc[i][1]);
          acc[i][2] = fmaf(a,b0v.z,acc[i][2]);
          acc[i][3] = fmaf(a,b0v.w,acc[i][3]);
          acc[i][4] = fmaf(a,b1v.x,acc[i][4]);
          acc[i][5] = fmaf(a,b1v.y,acc[i][5]);
          acc[i][6] = fmaf(a,b1v.z,acc[i][6]);
          acc[i][7] = fmaf(a,b1v.w,acc[i][7]);
        }
      }
    }
    __syncthreads();
  }
  #pragma unroll
  for (int i=0;i<4;i++){
    int row = n0 + ty*4 + i;
    if (row < N_NODES){
      float4 o0, o1;
      o0.x = acc[i][0] + bptr[wcol + tx*4 + 0];
      o0.y = acc[i][1] + bptr[wcol + tx*4 + 1];
      o0.z = acc[i][2] + bptr[wcol + tx*4 + 2];
      o0.w = acc[i][3] + bptr[wcol + tx*4 + 3];
      o1.x = acc[i][4] + bptr[wcol + 64 + tx*4 + 0];
      o1.y = acc[i][5] + bptr[wcol + 64 + tx*4 + 1];
      o1.z = acc[i][6] + bptr[wcol + 64 + tx*4 + 2];
      o1.w = acc[i][7] + bptr[wcol + 64 + tx*4 + 3];
      *(float4*)(out + (size_t)row*ostride + col0 + tx*4)      = o0;
      *(float4*)(out + (size_t)row*ostride + col0 + 64 + tx*4) = o1;
    }
  }
}

// ---------------- layer-1 fused logits + softmax + aggregate + skip + ELU ----------
// block per node; 8 heads x 32 channels. skip term pre-stored in hbuf; in-place.
__global__ __launch_bounds__(256) void k_attn1(const float* __restrict__ qkv1,
      const int* __restrict__ rowptr, const int* __restrict__ esrc,
      float* __restrict__ hbuf){
  __shared__ float lg[LCAP][8];
  int n = blockIdx.x;
  int t = threadIdx.x;
  int h = t >> 5, c = t & 31;
  int beg = rowptr[n], end = rowptr[n+1];
  float q = qkv1[(size_t)n*D3 + h*32 + c];
  float m = -INFINITY;
  for (int i = beg; i < end; i++){
    int src = esrc[i];
    float kv = qkv1[(size_t)src*D3 + 256 + h*32 + c];
    float p = q * kv;
    p += __shfl_xor(p, 1);
    p += __shfl_xor(p, 2);
    p += __shfl_xor(p, 4);
    p += __shfl_xor(p, 8);
    p += __shfl_xor(p, 16);
    p *= 0.17677669529663687f;          // 1/sqrt(32)
    int li = i - beg;
    if (c == 0 && li < LCAP) lg[li][h] = p;   // same-wave write/read: no barrier
    m = fmaxf(m, p);
  }
  float s = 0.f, acc = 0.f;
  for (int i = beg; i < end; i++){
    int src = esrc[i];
    int li = i - beg;
    float p;
    if (li < LCAP) p = lg[li][h];
    else {                               // ~never: recompute, bitwise identical
      float kv = qkv1[(size_t)src*D3 + 256 + h*32 + c];
      p = q * kv;
      p += __shfl_xor(p, 1);
      p += __shfl_xor(p, 2);
      p += __shfl_xor(p, 4);
      p += __shfl_xor(p, 8);
      p += __shfl_xor(p, 16);
      p *= 0.17677669529663687f;
    }
    float w = __expf(p - m);
    s += w;
    acc = fmaf(w, qkv1[(size_t)src*D3 + 512 + h*32 + c], acc);
  }
  float v = acc / (s + 1e-16f) + hbuf[(size_t)n*D1 + t];  // + skip (pre-stored)
  hbuf[(size_t)n*D1 + t] = v > 0.f ? v : expm1f(v);       // ELU, in-place
}

// ---------------- layer-2 GEMM: h[N,256] @ [w2q|w2k|w2v|w2s][256,10] ----------------
__global__ __launch_bounds__(256) void k_gemm2(const float* __restrict__ hin,
     const float* __restrict__ wq, const float* __restrict__ wk,
     const float* __restrict__ wv, const float* __restrict__ wsk,
     const float* __restrict__ bq, const float* __restrict__ bk,
     const float* __restrict__ bv, const float* __restrict__ bs,
     float* __restrict__ out){
  __shared__ float hs[64][68];
  __shared__ float wsm[64][40];
  int t = threadIdx.x;
  int r = t >> 2, g = t & 3;
  int n0 = blockIdx.x * 64;
  const float* bsel = g==0 ? bq : g==1 ? bk : g==2 ? bv : bs;
  float acc[10];
  #pragma unroll
  for (int j=0;j<10;j++) acc[j] = 0.f;

  for (int k0 = 0; k0 < D1; k0 += 64){
    #pragma unroll
    for (int q = 0; q < 4; q++){
      int L = (q*256 + t)*4;
      int row = L >> 6, col = L & 63;
      int gr = n0 + row;
      float4 vv = make_float4(0.f,0.f,0.f,0.f);
      if (gr < N_NODES) vv = *(const float4*)(hin + (size_t)gr*D1 + k0 + col);
      *(float4*)&hs[row][col] = vv;
    }
    for (int L = t; L < 64*40; L += 256){
      int row = L/40, cc = L%40;
      int sl = cc/10;
      const float* p = sl==0 ? wq : sl==1 ? wk : sl==2 ? wv : wsk;
      wsm[row][cc] = p[(size_t)(k0+row)*10 + (cc - sl*10)];
    }
    __syncthreads();
    for (int kk = 0; kk < 64; kk++){
      float a = hs[r][kk];
      #pragma unroll
      for (int j=0;j<10;j++) acc[j] = fmaf(a, wsm[kk][g*10+j], acc[j]);
    }
    __syncthreads();
  }
  int gr = n0 + r;
  if (gr < N_NODES){
    #pragma unroll
    for (int j=0;j<10;j++)
      out[(size_t)gr*D2ALL + g*10 + j] = acc[j] + bsel[j];
  }
}

// ---------------- layer-2 fused logits + softmax + aggregate + skip ----------------
// thread per node; q in registers; logits spilled to l2 (contiguous per node).
__global__ void k_agg2(const float* __restrict__ qkvs2, const int* __restrict__ rowptr,
    const int* __restrict__ esrc, float* __restrict__ l2, float* __restrict__ out){
  int n = blockIdx.x*blockDim.x + threadIdx.x;
  if (n >= N_NODES) return;
  int beg = rowptr[n], end = rowptr[n+1];
  float qv[10];
  #pragma unroll
  for (int j=0;j<10;j++) qv[j] = qkvs2[(size_t)n*D2ALL + j];
  float m = -INFINITY;
  for (int i = beg; i < end; i++){
    const float* kp = qkvs2 + (size_t)esrc[i]*D2ALL + 10;
    float sd = 0.f;
    #pragma unroll
    for (int j=0;j<10;j++) sd = fmaf(qv[j], kp[j], sd);
    sd *= 0.31622776601683794f;   // 1/sqrt(10)
    l2[i] = sd;
    m = fmaxf(m, sd);
  }
  float s = 0.f;
  float acc[10];
  #pragma unroll
  for (int j=0;j<10;j++) acc[j] = 0.f;
  for (int i = beg; i < end; i++){
    float w = __expf(l2[i] - m);
    s += w;
    const float* vp = qkvs2 + (size_t)esrc[i]*D2ALL + 20;
    #pragma unroll
    for (int j=0;j<10;j++) acc[j] = fmaf(w, vp[j], acc[j]);
  }
  float inv = 1.f/(s + 1e-16f);
  const float* sp = qkvs2 + (size_t)n*D2ALL + 30;
  #pragma unroll
  for (int j=0;j<10;j++) out[(size_t)n*10 + j] = acc[j]*inv + sp[j];
}

static inline size_t align256(size_t x){ return (x + 255) & ~(size_t)255; }

extern "C" void kernel_launch(void* const* d_in, const int* in_sizes, int n_in,
                              void* d_out, int out_size, void* d_ws, size_t ws_size,
                              hipStream_t stream) {
  const float* x   = (const float*)d_in[0];
  const int*   eiw = (const int*)d_in[1];
  const float* w1q=(const float*)d_in[2],  *b1q=(const float*)d_in[3];
  const float* w1k=(const float*)d_in[4],  *b1k=(const float*)d_in[5];
  const float* w1v=(const float*)d_in[6],  *b1v=(const float*)d_in[7];
  const float* w1s=(const float*)d_in[8],  *b1s=(const float*)d_in[9];
  const float* w2q=(const float*)d_in[10], *b2q=(const float*)d_in[11];
  const float* w2k=(const float*)d_in[12], *b2k=(const float*)d_in[13];
  const float* w2v=(const float*)d_in[14], *b2v=(const float*)d_in[15];
  const float* w2s=(const float*)d_in[16], *b2s=(const float*)d_in[17];

  // ---- workspace layout (aliased; peak 208.2 MB) ----
  const size_t offRow  = 0;
  const size_t offEsrc = align256((size_t)(N_NODES+1)*4);          // rowptr
  const size_t offHbuf = offEsrc + align256((size_t)N_EDGES*4);    // esrc
  const size_t offR    = offHbuf + (size_t)N_NODES*D1*4;           // hbuf
  const size_t REQ     = offR    + (size_t)N_NODES*D3*4;           // qkv region

  if (ws_size < REQ){   // diagnostic: clean wrong-answer instead of OOB crash
    k_zero<<<(out_size+255)/256, 256, 0, stream>>>((float*)d_out, out_size);
    return;
  }

  char* base = (char*)d_ws;
  int*   rowptr = (int*)(base + offRow);
  int*   esrc   = (int*)(base + offEsrc);
  float* hbuf   = (float*)(base + offHbuf);
  float* qkv1   = (float*)(base + offR);
  // CSR temps alias the qkv region (dead before k_lin writes it)
  int*   deg    = (int*)(base + offR);
  int*   cursor = (int*)(base + offR + align256((size_t)N_NODES*4));
  int*   s0     = (int*)(base + offR + 2*align256((size_t)N_NODES*4));
  int*   d0     = (int*)(base + offR + 2*align256((size_t)N_NODES*4) + align256((size_t)N_EDGES*4));
  // layer-2 buffers alias the qkv region (qkv dead after k_attn1)
  float* qkvs2  = (float*)(base + offR);
  float* l2     = (float*)(base + offR + align256((size_t)N_NODES*D2ALL*4));

  k_edges  <<<(N_EDGES+255)/256, 256, 0, stream>>>(eiw, s0, d0);
  hipMemsetAsync(deg, 0, (size_t)N_NODES*4, stream);
  k_count  <<<(N_EDGES+255)/256, 256, 0, stream>>>(d0, deg);
  k_scan   <<<1, 1024, 0, stream>>>(deg, rowptr, cursor);
  k_scatter<<<(N_EDGES+255)/256, 256, 0, stream>>>(s0, d0, cursor, esrc);

  k_lin<<<dim3(6, (N_NODES+63)/64), 256, 0, stream>>>(
      x, w1q, w1k, w1v, b1q, b1k, b1v, qkv1, D3);          // q|k|v
  k_lin<<<dim3(2, (N_NODES+63)/64), 256, 0, stream>>>(
      x, w1s, w1s, w1s, b1s, b1s, b1s, hbuf, D1);          // skip -> hbuf
  k_attn1<<<N_NODES, 256, 0, stream>>>(qkv1, rowptr, esrc, hbuf);

  k_gemm2<<<(N_NODES+63)/64, 256, 0, stream>>>(
      hbuf, w2q,w2k,w2v,w2s, b2q,b2k,b2v,b2s, qkvs2);
  k_agg2<<<(N_NODES+255)/256, 256, 0, stream>>>(qkvs2, rowptr, esrc, l2, (float*)d_out);
}

// Round 11
// 888.919 us; speedup vs baseline: 1.2105x; 1.2105x over previous
//
#include <hip/hip_runtime.h>
#include <math.h>

#define N_NODES 50000
#define N_EDGES 800000
#define IN_DIMC 128
#define D1 256      // heads*hid (layer-1 output width, also skip width)
#define D3 768      // q|k|v concat width
#define D2ALL 40    // layer-2 q|k|v|skip concat width

// ---------------- diagnostic fallback ----------------
__global__ void k_zero(float* __restrict__ out, int n){
  int i = blockIdx.x*blockDim.x + threadIdx.x;
  if (i < n) out[i] = 0.f;
}

// ---------------- edge decode: robust to int32 / int64 edge_index ----------------
__global__ void k_edges(const int* __restrict__ w, int* __restrict__ s0, int* __restrict__ d0){
  __shared__ int is64_s;
  if (threadIdx.x == 0){
    int acc = 0;
    #pragma unroll
    for (int j = 0; j < 17; j++) acc |= w[2*j+1];   // int64 hi-words are 0 (ids<50000)
    is64_s = (acc == 0);
  }
  __syncthreads();
  bool is64 = is64_s;
  int e = blockIdx.x*blockDim.x + threadIdx.x;
  if (e < N_EDGES){
    if (is64){ s0[e] = w[2*e];  d0[e] = w[2*(N_EDGES + e)]; }
    else     { s0[e] = w[e];    d0[e] = w[N_EDGES + e];     }
  }
}

// ---------------- CSR build ----------------
__global__ void k_count(const int* __restrict__ d0, int* __restrict__ deg){
  int e = blockIdx.x*blockDim.x + threadIdx.x;
  if (e < N_EDGES) atomicAdd(&deg[d0[e]], 1);
}

__global__ __launch_bounds__(1024) void k_scan(const int* __restrict__ deg,
                                               int* __restrict__ rowptr,
                                               int* __restrict__ cursor){
  __shared__ int wsum[16];
  __shared__ int carry_s;
  int t = threadIdx.x;
  int w = t >> 6, lane = t & 63;
  if (t == 0){ carry_s = 0; rowptr[0] = 0; }
  __syncthreads();
  for (int base = 0; base < N_NODES; base += 1024){
    int i = base + t;
    int v = (i < N_NODES) ? deg[i] : 0;
    int s = v;
    #pragma unroll
    for (int off = 1; off < 64; off <<= 1){
      int u = __shfl_up(s, off);
      if (lane >= off) s += u;
    }
    if (lane == 63) wsum[w] = s;
    __syncthreads();
    if (w == 0 && lane < 16){
      int ws = wsum[lane];
      #pragma unroll
      for (int off = 1; off < 16; off <<= 1){
        int u = __shfl_up(ws, off);
        if (lane >= off) ws += u;
      }
      wsum[lane] = ws;
    }
    __syncthreads();
    int waveoff = (w == 0) ? 0 : wsum[w-1];
    int incl = carry_s + waveoff + s;
    if (i < N_NODES){
      rowptr[i+1] = incl;
      cursor[i]   = incl - v;
    }
    __syncthreads();
    if (t == 1023) carry_s = incl;
    __syncthreads();
  }
}

__global__ void k_scatter(const int* __restrict__ s0, const int* __restrict__ d0,
                          int* __restrict__ cursor, int* __restrict__ esrc){
  int e = blockIdx.x*blockDim.x + threadIdx.x;
  if (e < N_EDGES){
    int slot = atomicAdd(&cursor[d0[e]], 1);
    esrc[slot] = s0[e];
  }
}

// ---------------- linear: x[N,128] @ w[128,256] column-tiles, 64x128 per block ----
// grid (8, nb): bx 0..5 -> q|k|v into qkv1 (stride 768), bx 6..7 -> skip into hbuf
__global__ __launch_bounds__(256) void k_lin(const float* __restrict__ x,
        const float* __restrict__ wq, const float* __restrict__ wk,
        const float* __restrict__ wv, const float* __restrict__ wsk,
        const float* __restrict__ bq, const float* __restrict__ bk,
        const float* __restrict__ bv, const float* __restrict__ bs,
        float* __restrict__ oqkv, float* __restrict__ oskip){
  __shared__ float xs[64][68];
  __shared__ float wls[64][128];
  int t  = threadIdx.x;
  int ty = t >> 4, tx = t & 15;
  int n0  = blockIdx.y * 64;
  int bx  = blockIdx.x;
  int sel  = bx >> 1;                  // 0..3 -> q,k,v,skip
  int wcol = (bx & 1) * 128;
  const float* wptr = sel==0 ? wq : sel==1 ? wk : sel==2 ? wv : wsk;
  const float* bptr = sel==0 ? bq : sel==1 ? bk : sel==2 ? bv : bs;
  float* out  = (sel < 3) ? oqkv : oskip;
  int ostride = (sel < 3) ? D3 : D1;
  int col0    = (sel < 3) ? sel*256 + wcol : wcol;

  float acc[4][8];
  #pragma unroll
  for (int i=0;i<4;i++)
    #pragma unroll
    for (int j=0;j<8;j++) acc[i][j] = 0.f;

  for (int k0 = 0; k0 < IN_DIMC; k0 += 64){
    #pragma unroll
    for (int q = 0; q < 4; q++){
      int L = (q*256 + t)*4;
      int row = L >> 6, col = L & 63;
      int gr = n0 + row;
      float4 vv = make_float4(0.f,0.f,0.f,0.f);
      if (gr < N_NODES) vv = *(const float4*)(x + (size_t)gr*IN_DIMC + k0 + col);
      *(float4*)&xs[row][col] = vv;
    }
    #pragma unroll
    for (int q = 0; q < 8; q++){
      int L = (q*256 + t)*4;
      int row = L >> 7, col = L & 127;
      float4 vv = *(const float4*)(wptr + (size_t)(k0+row)*256 + wcol + col);
      *(float4*)&wls[row][col] = vv;
    }
    __syncthreads();
    for (int kk = 0; kk < 64; kk += 4){
      float4 aq[4];
      #pragma unroll
      for (int i=0;i<4;i++) aq[i] = *(const float4*)&xs[ty*4+i][kk];
      #pragma unroll
      for (int u=0;u<4;u++){
        float4 b0v = *(const float4*)&wls[kk+u][tx*4];
        float4 b1v = *(const float4*)&wls[kk+u][64 + tx*4];
        #pragma unroll
        for (int i=0;i<4;i++){
          float a = ((const float*)&aq[i])[u];
          acc[i][0] = fmaf(a,b0v.x,acc[i][0]);
          acc[i][1] = fmaf(a,b0v.y,acc[i][1]);
          acc[i][2] = fmaf(a,b0v.z,acc[i][2]);
          acc[i][3] = fmaf(a,b0v.w,acc[i][3]);
          acc[i][4] = fmaf(a,b1v.x,acc[i][4]);
          acc[i][5] = fmaf(a,b1v.y,acc[i][5]);
          acc[i][6] = fmaf(a,b1v.z,acc[i][6]);
          acc[i][7] = fmaf(a,b1v.w,acc[i][7]);
        }
      }
    }
    __syncthreads();
  }
  #pragma unroll
  for (int i=0;i<4;i++){
    int row = n0 + ty*4 + i;
    if (row < N_NODES){
      float4 o0, o1;
      o0.x = acc[i][0] + bptr[wcol + tx*4 + 0];
      o0.y = acc[i][1] + bptr[wcol + tx*4 + 1];
      o0.z = acc[i][2] + bptr[wcol + tx*4 + 2];
      o0.w = acc[i][3] + bptr[wcol + tx*4 + 3];
      o1.x = acc[i][4] + bptr[wcol + 64 + tx*4 + 0];
      o1.y = acc[i][5] + bptr[wcol + 64 + tx*4 + 1];
      o1.z = acc[i][6] + bptr[wcol + 64 + tx*4 + 2];
      o1.w = acc[i][7] + bptr[wcol + 64 + tx*4 + 3];
      *(float4*)(out + (size_t)row*ostride + col0 + tx*4)      = o0;
      *(float4*)(out + (size_t)row*ostride + col0 + 64 + tx*4) = o1;
    }
  }
}

// ---------------- layer-1 fused attention: ONE WAVE PER NODE ----------------
// lane l: head h=l>>3, quad j=l&7 -> channels [4l,4l+4). One dwordx4 per wave
// reads a whole 1KB k-row (and one for v). Online softmax, no LDS, no 2nd pass.
__global__ __launch_bounds__(256) void k_attn1(const float* __restrict__ qkv1,
      const int* __restrict__ rowptr, const int* __restrict__ esrc,
      float* __restrict__ hbuf){
  int wid  = threadIdx.x >> 6;
  int lane = threadIdx.x & 63;
  int n = blockIdx.x*4 + wid;
  if (n >= N_NODES) return;
  int beg = rowptr[n], end = rowptr[n+1];

  float4 q = *(const float4*)(qkv1 + (size_t)n*D3 + lane*4);
  const float sc = 0.17677669529663687f;     // 1/sqrt(32), folded into q
  q.x*=sc; q.y*=sc; q.z*=sc; q.w*=sc;

  float m = -INFINITY, s = 0.f;
  float4 acc = make_float4(0.f,0.f,0.f,0.f);
  int src = (beg < end) ? esrc[beg] : 0;
  for (int i = beg; i < end; i++){
    int nsrc = (i+1 < end) ? esrc[i+1] : 0;   // prefetch: breaks addr dependence
    const float* kr = qkv1 + (size_t)src*D3 + 256;
    const float* vr = qkv1 + (size_t)src*D3 + 512;
    float4 kv = *(const float4*)(kr + lane*4);
    float4 vv = *(const float4*)(vr + lane*4);
    float p = q.x*kv.x + q.y*kv.y + q.z*kv.z + q.w*kv.w;
    p += __shfl_xor(p, 1);
    p += __shfl_xor(p, 2);
    p += __shfl_xor(p, 4);     // all 8 lanes of the head group hold the full dot
    float mn = fmaxf(m, p);
    float c  = __expf(m - mn); // 0 on first iter (m=-inf), 1 while max unchanged
    float w  = __expf(p - mn);
    s = s*c + w;
    acc.x = acc.x*c + w*vv.x;
    acc.y = acc.y*c + w*vv.y;
    acc.z = acc.z*c + w*vv.z;
    acc.w = acc.w*c + w*vv.w;
    m = mn;
    src = nsrc;
  }
  float inv = 1.f/(s + 1e-16f);
  size_t o = (size_t)n*D1 + lane*4;
  float4 sk = *(const float4*)(hbuf + o);    // skip term (pre-stored)
  float4 r;
  r.x = acc.x*inv + sk.x;
  r.y = acc.y*inv + sk.y;
  r.z = acc.z*inv + sk.z;
  r.w = acc.w*inv + sk.w;
  r.x = r.x > 0.f ? r.x : expm1f(r.x);       // ELU
  r.y = r.y > 0.f ? r.y : expm1f(r.y);
  r.z = r.z > 0.f ? r.z : expm1f(r.z);
  r.w = r.w > 0.f ? r.w : expm1f(r.w);
  *(float4*)(hbuf + o) = r;
}

// ---------------- layer-2 GEMM: h[N,256] @ [w2q|w2k|w2v|w2s][256,10] ----------------
__global__ __launch_bounds__(256) void k_gemm2(const float* __restrict__ hin,
     const float* __restrict__ wq, const float* __restrict__ wk,
     const float* __restrict__ wv, const float* __restrict__ wsk,
     const float* __restrict__ bq, const float* __restrict__ bk,
     const float* __restrict__ bv, const float* __restrict__ bs,
     float* __restrict__ out){
  __shared__ float hs[64][68];
  __shared__ float wsm[64][40];
  int t = threadIdx.x;
  int r = t >> 2, g = t & 3;
  int n0 = blockIdx.x * 64;
  const float* bsel = g==0 ? bq : g==1 ? bk : g==2 ? bv : bs;
  float acc[10];
  #pragma unroll
  for (int j=0;j<10;j++) acc[j] = 0.f;

  for (int k0 = 0; k0 < D1; k0 += 64){
    #pragma unroll
    for (int q = 0; q < 4; q++){
      int L = (q*256 + t)*4;
      int row = L >> 6, col = L & 63;
      int gr = n0 + row;
      float4 vv = make_float4(0.f,0.f,0.f,0.f);
      if (gr < N_NODES) vv = *(const float4*)(hin + (size_t)gr*D1 + k0 + col);
      *(float4*)&hs[row][col] = vv;
    }
    for (int L = t; L < 64*40; L += 256){
      int row = L/40, cc = L%40;
      int sl = cc/10;
      const float* p = sl==0 ? wq : sl==1 ? wk : sl==2 ? wv : wsk;
      wsm[row][cc] = p[(size_t)(k0+row)*10 + (cc - sl*10)];
    }
    __syncthreads();
    for (int kk = 0; kk < 64; kk++){
      float a = hs[r][kk];
      #pragma unroll
      for (int j=0;j<10;j++) acc[j] = fmaf(a, wsm[kk][g*10+j], acc[j]);
    }
    __syncthreads();
  }
  int gr = n0 + r;
  if (gr < N_NODES){
    #pragma unroll
    for (int j=0;j<10;j++)
      out[(size_t)gr*D2ALL + g*10 + j] = acc[j] + bsel[j];
  }
}

// ---------------- layer-2 fused logits + softmax + aggregate + skip ----------------
__global__ void k_agg2(const float* __restrict__ qkvs2, const int* __restrict__ rowptr,
    const int* __restrict__ esrc, float* __restrict__ l2, float* __restrict__ out){
  int n = blockIdx.x*blockDim.x + threadIdx.x;
  if (n >= N_NODES) return;
  int beg = rowptr[n], end = rowptr[n+1];
  float qv[10];
  #pragma unroll
  for (int j=0;j<10;j++) qv[j] = qkvs2[(size_t)n*D2ALL + j];
  float m = -INFINITY;
  for (int i = beg; i < end; i++){
    const float* kp = qkvs2 + (size_t)esrc[i]*D2ALL + 10;
    float sd = 0.f;
    #pragma unroll
    for (int j=0;j<10;j++) sd = fmaf(qv[j], kp[j], sd);
    sd *= 0.31622776601683794f;   // 1/sqrt(10)
    l2[i] = sd;
    m = fmaxf(m, sd);
  }
  float s = 0.f;
  float acc[10];
  #pragma unroll
  for (int j=0;j<10;j++) acc[j] = 0.f;
  for (int i = beg; i < end; i++){
    float w = __expf(l2[i] - m);
    s += w;
    const float* vp = qkvs2 + (size_t)esrc[i]*D2ALL + 20;
    #pragma unroll
    for (int j=0;j<10;j++) acc[j] = fmaf(w, vp[j], acc[j]);
  }
  float inv = 1.f/(s + 1e-16f);
  const float* sp = qkvs2 + (size_t)n*D2ALL + 30;
  #pragma unroll
  for (int j=0;j<10;j++) out[(size_t)n*10 + j] = acc[j]*inv + sp[j];
}

static inline size_t align256(size_t x){ return (x + 255) & ~(size_t)255; }

extern "C" void kernel_launch(void* const* d_in, const int* in_sizes, int n_in,
                              void* d_out, int out_size, void* d_ws, size_t ws_size,
                              hipStream_t stream) {
  const float* x   = (const float*)d_in[0];
  const int*   eiw = (const int*)d_in[1];
  const float* w1q=(const float*)d_in[2],  *b1q=(const float*)d_in[3];
  const float* w1k=(const float*)d_in[4],  *b1k=(const float*)d_in[5];
  const float* w1v=(const float*)d_in[6],  *b1v=(const float*)d_in[7];
  const float* w1s=(const float*)d_in[8],  *b1s=(const float*)d_in[9];
  const float* w2q=(const float*)d_in[10], *b2q=(const float*)d_in[11];
  const float* w2k=(const float*)d_in[12], *b2k=(const float*)d_in[13];
  const float* w2v=(const float*)d_in[14], *b2v=(const float*)d_in[15];
  const float* w2s=(const float*)d_in[16], *b2s=(const float*)d_in[17];

  // ---- workspace layout (aliased; peak 208.2 MB) ----
  const size_t offRow  = 0;
  const size_t offEsrc = align256((size_t)(N_NODES+1)*4);          // rowptr
  const size_t offHbuf = offEsrc + align256((size_t)N_EDGES*4);    // esrc
  const size_t offR    = offHbuf + (size_t)N_NODES*D1*4;           // hbuf
  const size_t REQ     = offR    + (size_t)N_NODES*D3*4;           // qkv region

  if (ws_size < REQ){   // diagnostic: clean wrong-answer instead of OOB crash
    k_zero<<<(out_size+255)/256, 256, 0, stream>>>((float*)d_out, out_size);
    return;
  }

  char* base = (char*)d_ws;
  int*   rowptr = (int*)(base + offRow);
  int*   esrc   = (int*)(base + offEsrc);
  float* hbuf   = (float*)(base + offHbuf);
  float* qkv1   = (float*)(base + offR);
  // CSR temps alias the qkv region (dead before k_lin writes it)
  int*   deg    = (int*)(base + offR);
  int*   cursor = (int*)(base + offR + align256((size_t)N_NODES*4));
  int*   s0     = (int*)(base + offR + 2*align256((size_t)N_NODES*4));
  int*   d0     = (int*)(base + offR + 2*align256((size_t)N_NODES*4) + align256((size_t)N_EDGES*4));
  // layer-2 buffers alias the qkv region (qkv dead after k_attn1)
  float* qkvs2  = (float*)(base + offR);
  float* l2     = (float*)(base + offR + align256((size_t)N_NODES*D2ALL*4));

  k_edges  <<<(N_EDGES+255)/256, 256, 0, stream>>>(eiw, s0, d0);
  hipMemsetAsync(deg, 0, (size_t)N_NODES*4, stream);
  k_count  <<<(N_EDGES+255)/256, 256, 0, stream>>>(d0, deg);
  k_scan   <<<1, 1024, 0, stream>>>(deg, rowptr, cursor);
  k_scatter<<<(N_EDGES+255)/256, 256, 0, stream>>>(s0, d0, cursor, esrc);

  k_lin<<<dim3(8, (N_NODES+63)/64), 256, 0, stream>>>(
      x, w1q,w1k,w1v,w1s, b1q,b1k,b1v,b1s, qkv1, hbuf);   // q|k|v + skip
  k_attn1<<<(N_NODES+3)/4, 256, 0, stream>>>(qkv1, rowptr, esrc, hbuf);

  k_gemm2<<<(N_NODES+63)/64, 256, 0, stream>>>(
      hbuf, w2q,w2k,w2v,w2s, b2q,b2k,b2v,b2s, qkvs2);
  k_agg2<<<(N_NODES+255)/256, 256, 0, stream>>>(qkvs2, rowptr, esrc, l2, (float*)d_out);
}